// Round 5
// baseline (43.557 us; speedup 1.0000x reference)
//
#include <hip/hip_runtime.h>

// ---------------- problem constants ----------------
constexpr int   kB       = 1024;
constexpr int   kH       = 28;
constexpr int   kW       = 28;
constexpr int   kCells   = kB * kH * kW;        // 802816
constexpr int   kCh      = 30;                  // 10 + 20 classes
constexpr int   kCellsPB = 512;                 // cells per block
constexpr int   kThreads = 256;
constexpr int   kBlocks  = kCells / kCellsPB;   // 1568
constexpr int   kIters   = kCellsPB * kCh / 4 / kThreads;  // 3840/256 = 15
constexpr float kLCoord = 5.0f, kLObj = 1.0f, kLNoobj = 0.5f;

__device__ __forceinline__ float iou_decoded(
    float pcx, float pcy, float psw, float psh,
    float tcx, float tcy, float tsw, float tsh)
{
    float aw = tsw * tsw, ah = tsh * tsh;
    float a0 = tcx - aw * 0.5f, a1 = tcy - ah * 0.5f;
    float a2 = tcx + aw * 0.5f, a3 = tcy + ah * 0.5f;
    float bw = psw * psw, bh = psh * psh;
    float b0 = pcx - bw * 0.5f, b1 = pcy - bh * 0.5f;
    float b2 = pcx + bw * 0.5f, b3 = pcy + bh * 0.5f;
    float x0 = fmaxf(a0, b0), y0 = fmaxf(a1, b1);
    float x1 = fminf(a2, b2), y1 = fminf(a3, b3);
    float inter  = fmaxf(x1 - x0, 0.0f) * fmaxf(y1 - y0, 0.0f);
    float area_a = (a2 - a0) * (a3 - a1);
    float area_b = (b2 - b0) * (b3 - b1);
    return inter / (area_a + area_b - inter + 1e-10f);
}

// ws layout: ws[m*kBlocks + b], m: 0=cls 1=resp 2=off 3=neg (unscaled sums)
__global__ __launch_bounds__(256) void yolo_loss_main(
    const float* __restrict__ pred, const float* __restrict__ meta,
    float* __restrict__ ws)
{
    const int t  = threadIdx.x;
    const int c0 = blockIdx.x * kCellsPB;

    // ================= phase 1: coalesced float4 stream, element-local noobj =================
    // Block span: 512 cells * 30 floats = 15360 floats = 3840 float4 (base 16B-aligned:
    // c0*30*4 = blockIdx*61440 bytes). Thread t reads float4 j = t + 256*i, i=0..14.
    // Element with flat channel ch = f mod 30: ch==4 -> (p4, resp); ch==9 -> (p9, resp)
    // in the SAME lane (pred/meta share layout, meta[4]==meta[9]==resp).
    float l_neg = 0.0f;
    {
        const size_t fbase = (size_t)c0 * kCh;
        const float4* p4 = reinterpret_cast<const float4*>(pred + fbase);
        const float4* m4 = reinterpret_cast<const float4*>(meta + fbase);

        int ch = (4 * t) % 30;   // channel of element .x this iteration; +=4 (mod 30)/iter
        #pragma unroll
        for (int i = 0; i < kIters; ++i) {
            const int j = t + kThreads * i;
            float4 p = p4[j];
            float4 m = m4[j];

            int c = ch;
            {   // .x
                bool sel = (c == 4) | (c == 9);
                float d = p.x - m.x;
                l_neg += (sel && (m.x < 1.0f)) ? d * d : 0.0f;
            }
            c++; if (c == 30) c = 0;
            {   // .y
                bool sel = (c == 4) | (c == 9);
                float d = p.y - m.y;
                l_neg += (sel && (m.y < 1.0f)) ? d * d : 0.0f;
            }
            c++; if (c == 30) c = 0;
            {   // .z
                bool sel = (c == 4) | (c == 9);
                float d = p.z - m.z;
                l_neg += (sel && (m.z < 1.0f)) ? d * d : 0.0f;
            }
            c++; if (c == 30) c = 0;
            {   // .w
                bool sel = (c == 4) | (c == 9);
                float d = p.w - m.w;
                l_neg += (sel && (m.w < 1.0f)) ? d * d : 0.0f;
            }
            ch += 4; if (ch >= 30) ch -= 30;   // advance 1024 floats: 1024 mod 30 = 4
        }
    }

    // ================= phase 2: positive cells (~2%), data is L2-hot =================
    float l_cls = 0.0f, l_resp = 0.0f, l_off = 0.0f;
    #pragma unroll
    for (int u = 0; u < 2; ++u) {
        const int cg = c0 + t + u * kThreads;        // this thread's cell (2 per thread)
        const float* pc = pred + (size_t)cg * kCh;
        const float* mc = meta + (size_t)cg * kCh;
        float resp = mc[4];                          // L1/L2 hit (just streamed)
        if (resp + resp > 0.9f) {
            float pv[10], mv[10];
            const float2* pp = reinterpret_cast<const float2*>(pc);
            const float2* mm = reinterpret_cast<const float2*>(mc);
            #pragma unroll
            for (int i = 0; i < 5; ++i) {
                float2 a = pp[i]; pv[2*i] = a.x; pv[2*i+1] = a.y;
                float2 b = mm[i]; mv[2*i] = b.x; mv[2*i+1] = b.y;
            }
            const float pos = (mv[4] + mv[9] > 0.9f) ? 1.0f : 0.0f;

            float iou0 = iou_decoded(pv[0], pv[1], pv[2], pv[3], mv[0], mv[1], mv[2], mv[3]);
            float iou1 = iou_decoded(pv[5], pv[6], pv[7], pv[8], mv[5], mv[6], mv[7], mv[8]);
            bool  best1 = (iou1 > iou0);             // first-max tie-break => strict >

            float iou_b    = best1 ? iou1  : iou0;
            float p_resp_b = best1 ? pv[9] : pv[4];
            float dr = p_resp_b - iou_b;
            l_resp += pos * dr * dr;

            float off_acc = 0.0f;
            #pragma unroll
            for (int k = 0; k < 4; ++k) {
                float pb = best1 ? pv[5 + k] : pv[k];
                float tb = best1 ? mv[5 + k] : mv[k];
                float d  = pb - tb;
                off_acc += d * d;
            }
            l_off += pos * off_acc;

            // class loss streamed in float2 pairs to keep registers low
            float cls_acc = 0.0f;
            const float2* pcl = reinterpret_cast<const float2*>(pc + 10);
            const float2* mcl = reinterpret_cast<const float2*>(mc + 10);
            #pragma unroll
            for (int i = 0; i < 10; ++i) {
                float2 a = pcl[i], b = mcl[i];
                float d0 = a.x - b.x, d1 = a.y - b.y;
                cls_acc += d0 * d0 + d1 * d1;
            }
            l_cls += pos * cls_acc;
            // NOTE: noobj term for this cell was already handled in phase 1
            // (mask t_resp<1 is false for resp==1, so it contributes 0 anyway).
        }
    }

    // ================= reduction: wave shuffle -> LDS -> per-block stores =================
    #pragma unroll
    for (int off = 32; off > 0; off >>= 1) {
        l_cls  += __shfl_down(l_cls,  off);
        l_resp += __shfl_down(l_resp, off);
        l_off  += __shfl_down(l_off,  off);
        l_neg  += __shfl_down(l_neg,  off);
    }

    __shared__ float red[4][4];  // [metric][wave]
    const int lane = t & 63;
    const int wid  = t >> 6;
    if (lane == 0) {
        red[0][wid] = l_cls;
        red[1][wid] = l_resp;
        red[2][wid] = l_off;
        red[3][wid] = l_neg;
    }
    __syncthreads();
    if (t == 0) {
        const int b = blockIdx.x;
        ws[0 * kBlocks + b] = red[0][0] + red[0][1] + red[0][2] + red[0][3];
        ws[1 * kBlocks + b] = red[1][0] + red[1][1] + red[1][2] + red[1][3];
        ws[2 * kBlocks + b] = red[2][0] + red[2][1] + red[2][2] + red[2][3];
        ws[3 * kBlocks + b] = red[3][0] + red[3][1] + red[3][2] + red[3][3];
    }
}

// Single-block deterministic reduce of the 4 x 1568 partials + finalize.
// out: (loss_sum, loss_pos_response, loss_neg_response, loss_pos_cls, loss_pos_offset)
__global__ __launch_bounds__(1024) void yolo_loss_reduce(
    const float* __restrict__ ws, float* __restrict__ out)
{
    const int t = threadIdx.x;
    float acc[4] = {0.0f, 0.0f, 0.0f, 0.0f};
    #pragma unroll
    for (int m = 0; m < 4; ++m) {
        for (int i = t; i < kBlocks; i += 1024) {   // coalesced
            acc[m] += ws[m * kBlocks + i];
        }
    }
    #pragma unroll
    for (int off = 32; off > 0; off >>= 1) {
        acc[0] += __shfl_down(acc[0], off);
        acc[1] += __shfl_down(acc[1], off);
        acc[2] += __shfl_down(acc[2], off);
        acc[3] += __shfl_down(acc[3], off);
    }
    __shared__ float red[4][16];
    const int lane = t & 63;
    const int wid  = t >> 6;
    if (lane == 0) {
        red[0][wid] = acc[0];
        red[1][wid] = acc[1];
        red[2][wid] = acc[2];
        red[3][wid] = acc[3];
    }
    __syncthreads();
    if (t == 0) {
        float s[4];
        #pragma unroll
        for (int m = 0; m < 4; ++m) {
            float v = 0.0f;
            #pragma unroll
            for (int w = 0; w < 16; ++w) v += red[m][w];
            s[m] = v;
        }
        float inv_b  = 1.0f / (float)kB;
        float s_cls  = s[0] * inv_b;
        float s_resp = s[1] * inv_b * kLObj;
        float s_off  = s[2] * inv_b * kLCoord;
        float s_neg  = s[3] * inv_b * kLNoobj;
        out[0] = s_neg + s_resp + s_off + s_cls;  // reference addition order
        out[1] = s_resp;
        out[2] = s_neg;
        out[3] = s_cls;
        out[4] = s_off;
    }
}

extern "C" void kernel_launch(void* const* d_in, const int* in_sizes, int n_in,
                              void* d_out, int out_size, void* d_ws, size_t ws_size,
                              hipStream_t stream) {
    const float* pred = (const float*)d_in[0];
    const float* meta = (const float*)d_in[1];
    float* out = (float*)d_out;
    float* ws  = (float*)d_ws;

    // No ws zeroing needed: every ws slot [0, 4*kBlocks) is written by main.
    yolo_loss_main<<<kBlocks, kThreads, 0, stream>>>(pred, meta, ws);
    yolo_loss_reduce<<<1, 1024, 0, stream>>>(ws, out);
}